// Round 16
// baseline (103.935 us; speedup 1.0000x reference)
//
#include <hip/hip_runtime.h>

#define PI_F 3.14159265358979323846f

typedef _Float16 h2t __attribute__((ext_vector_type(2)));
typedef __fp16 fp16x2 __attribute__((ext_vector_type(2)));
typedef _Float16 f16x8 __attribute__((ext_vector_type(8)));
typedef float f32x4 __attribute__((ext_vector_type(4)));
typedef unsigned int uint32;

__device__ __forceinline__ uint32 packh(float a, float b) {   // RNE
    h2t h = {(_Float16)a, (_Float16)b};
    return __builtin_bit_cast(uint32, h);
}
__device__ __forceinline__ uint32 pkrtz(float a, float b) {   // fast, staging
    fp16x2 h = __builtin_amdgcn_cvt_pkrtz(a, b);
    return __builtin_bit_cast(uint32, h);
}

// ---------------- K1: conv1 via MFMA 16x16x32_f16, XOR-swizzled LDS ----------------
// x:(8,4,128,128,8) -> h1:(8,8,61,61,8).
// tin dword idx = pos*16 + (w ^ (pos&7))*2 + icp   (pos = r*15+c).
// B-fragments packed in-block into wl (no prep kernel): wl[(ks*64+lane)*4 + h*2+icp],
// tap = 8ks + (lane>>4) + 4h, oc = lane&15 (zero-padded).
__global__ __launch_bounds__(256) void k_conv1(const float* __restrict__ x,
                                               const float* __restrict__ w1,
                                               const float* __restrict__ b1,
                                               float* __restrict__ h1) {
    const int b = blockIdx.y;
    const int ty = blockIdx.x >> 4, tx = blockIdx.x & 15;   // 16 x 16 tiles
    const int py0 = ty * 4, px0 = tx * 4;
    const int iy0 = py0 * 2, ix0 = px0 * 2;

    __shared__ uint32 tin[14 * 15 * 16];
    __shared__ uint32 wl[1792];

    const int tid = threadIdx.x;

    // pack B fragments into LDS (w1 is 6.3 KB, L2-hot)
    for (int i = tid; i < 1792; i += 256) {
        const int idx4 = i >> 2, rem = i & 3;
        const int h = rem >> 1, icp = rem & 1;
        const int oc = idx4 & 15, kcg = idx4 >> 4;       // kcg = ks*4 + c
        const int ks = kcg >> 2, c = kcg & 3;
        const int tap = 8 * ks + c + 4 * h;
        uint32 v = 0;
        if (tap < 49 && oc < 8)
            v = packh(w1[(oc * 4 + 2 * icp) * 49 + tap],
                      w1[(oc * 4 + 2 * icp + 1) * 49 + tap]);
        wl[i] = v;
    }

    const float* xb = x + (size_t)b * 4 * 131072;
    for (int s = tid; s < 392; s += 256) {
        const int r = s / 28, rem = s % 28, c = rem >> 1, wqs = rem & 1;
        const int row = min(iy0 + r, 127), col = min(ix0 + c, 127);
        const float* base = xb + ((size_t)row * 128 + col) * 8 + wqs * 4;
        const float4 f0 = *reinterpret_cast<const float4*>(base);
        const float4 f1 = *reinterpret_cast<const float4*>(base + 131072);
        const float4 f2 = *reinterpret_cast<const float4*>(base + 262144);
        const float4 f3 = *reinterpret_cast<const float4*>(base + 393216);
        const int pos = r * 15 + c;
        const int sw = pos & 7;
        const int bi = pos * 16;
        *reinterpret_cast<uint2*>(&tin[bi + (((wqs * 4 + 0) ^ sw) << 1)]) =
            make_uint2(pkrtz(f0.x, f1.x), pkrtz(f2.x, f3.x));
        *reinterpret_cast<uint2*>(&tin[bi + (((wqs * 4 + 1) ^ sw) << 1)]) =
            make_uint2(pkrtz(f0.y, f1.y), pkrtz(f2.y, f3.y));
        *reinterpret_cast<uint2*>(&tin[bi + (((wqs * 4 + 2) ^ sw) << 1)]) =
            make_uint2(pkrtz(f0.z, f1.z), pkrtz(f2.z, f3.z));
        *reinterpret_cast<uint2*>(&tin[bi + (((wqs * 4 + 3) ^ sw) << 1)]) =
            make_uint2(pkrtz(f0.w, f1.w), pkrtz(f2.w, f3.w));
    }

    const int lane = tid & 63;
    const int wv   = tid >> 6;
    const int kc   = lane >> 4;
    const int arow = lane & 15;
    const int q    = arow >> 2, cp = arow & 3;
    const int cpy  = cp >> 1,  cpx = cp & 1;

    int offp[7][2], sw1[7][2];
#pragma unroll
    for (int ks = 0; ks < 7; ++ks) {
#pragma unroll
        for (int h = 0; h < 2; ++h) {
            int tap = 8 * ks + kc + 4 * h;
            if (tap > 48) tap = 48;
            const int kd = tap / 7, kh = tap % 7;
            const int pos = (2 * wv + cpy + kd) * 15 + (2 * q + cpx + kh);
            offp[ks][h] = pos * 16;
            sw1[ks][h]  = pos & 7;
        }
    }

    __syncthreads();

    f16x8 Bf[7];
#pragma unroll
    for (int ks = 0; ks < 7; ++ks) {
        const uint4 t = *reinterpret_cast<const uint4*>(&wl[(ks * 64 + lane) * 4]);
        Bf[ks] = __builtin_bit_cast(f16x8, t);
    }

    f32x4 acc[8];
#pragma unroll
    for (int w = 0; w < 8; ++w) acc[w] = (f32x4)(0.f);

#pragma unroll
    for (int w = 0; w < 8; ++w) {
#pragma unroll
        for (int ks = 0; ks < 7; ++ks) {
            const uint2 lo = *reinterpret_cast<const uint2*>(
                &tin[offp[ks][0] + (((w ^ sw1[ks][0])) << 1)]);
            const uint2 hi = *reinterpret_cast<const uint2*>(
                &tin[offp[ks][1] + (((w ^ sw1[ks][1])) << 1)]);
            const uint4 a4 = make_uint4(lo.x, lo.y, hi.x, hi.y);
            acc[w] = __builtin_amdgcn_mfma_f32_16x16x32_f16(
                __builtin_bit_cast(f16x8, a4), Bf[ks], acc[w], 0, 0, 0);
        }
    }

    const int oc = lane & 15, qo = lane >> 4;
    const int pi = py0 + wv, pjg = px0 + qo;
    if (oc < 8 && pi < 61 && pjg < 61) {
        const float bb = b1[oc];
        float vals[8];
#pragma unroll
        for (int w = 0; w < 8; ++w) {
            const float m = fmaxf(fmaxf(acc[w][0], acc[w][1]), fmaxf(acc[w][2], acc[w][3]));
            vals[w] = fmaxf(m + bb, 0.f);
        }
        float* base = h1 + ((((size_t)b * 8 + oc) * 61 + pi) * 61 + pjg) * 8;
        *reinterpret_cast<float4*>(base)     = make_float4(vals[0], vals[1], vals[2], vals[3]);
        *reinterpret_cast<float4*>(base + 4) = make_float4(vals[4], vals[5], vals[6], vals[7]);
    }
}

// ---------------- K2: conv2 via MFMA 16x16x32_f16, XOR-swizzled LDS ----------------
// tin dword idx = pos*32 + (w ^ (pos&7))*4 + d   (pos = r*12+c).  B packed in-block.
__global__ __launch_bounds__(256) void k_conv2(const float* __restrict__ h1,
                                               const float* __restrict__ w2,
                                               const float* __restrict__ b2,
                                               float* __restrict__ h2) {
    const int b = blockIdx.y;
    const int ty = blockIdx.x / 7, tx = blockIdx.x % 7;    // 7 x 7 tiles of 4x4 pooled
    const int py0 = ty * 4, px0 = tx * 4;
    const int iy0 = py0 * 2, ix0 = px0 * 2;

    __shared__ uint32 tin[12 * 12 * 32];
    __shared__ uint32 wl[1792];

    const int tid = threadIdx.x;

    for (int i = tid; i < 1792; i += 256) {
        const int idx4 = i >> 2, d = i & 3;
        const int oc = idx4 & 15, kcg = idx4 >> 4;
        const int ks = kcg >> 2, c = kcg & 3;
        const int tap = 4 * ks + c;
        uint32 v = 0;
        if (tap < 25 && oc < 10)
            v = packh(w2[(oc * 8 + 2 * d) * 25 + tap],
                      w2[(oc * 8 + 2 * d + 1) * 25 + tap]);
        wl[i] = v;
    }

    const float* hb = h1 + (size_t)b * 8 * 29768;
    for (int s = tid; s < 288; s += 256) {
        const int pos = s >> 1, wqs = s & 1;
        const int r = pos / 12, c = pos % 12;
        const float* base = hb + ((size_t)(iy0 + r) * 61 + ix0 + c) * 8 + wqs * 4;
        const float4 f0 = *reinterpret_cast<const float4*>(base);
        const float4 f1 = *reinterpret_cast<const float4*>(base + 29768);
        const float4 f2 = *reinterpret_cast<const float4*>(base + 2 * 29768);
        const float4 f3 = *reinterpret_cast<const float4*>(base + 3 * 29768);
        const float4 f4 = *reinterpret_cast<const float4*>(base + 4 * 29768);
        const float4 f5 = *reinterpret_cast<const float4*>(base + 5 * 29768);
        const float4 f6 = *reinterpret_cast<const float4*>(base + 6 * 29768);
        const float4 f7 = *reinterpret_cast<const float4*>(base + 7 * 29768);
        const int sw = pos & 7;
        const int bi = pos * 32;
        *reinterpret_cast<uint4*>(&tin[bi + (((wqs * 4 + 0) ^ sw) << 2)]) =
            make_uint4(pkrtz(f0.x, f1.x), pkrtz(f2.x, f3.x), pkrtz(f4.x, f5.x), pkrtz(f6.x, f7.x));
        *reinterpret_cast<uint4*>(&tin[bi + (((wqs * 4 + 1) ^ sw) << 2)]) =
            make_uint4(pkrtz(f0.y, f1.y), pkrtz(f2.y, f3.y), pkrtz(f4.y, f5.y), pkrtz(f6.y, f7.y));
        *reinterpret_cast<uint4*>(&tin[bi + (((wqs * 4 + 2) ^ sw) << 2)]) =
            make_uint4(pkrtz(f0.z, f1.z), pkrtz(f2.z, f3.z), pkrtz(f4.z, f5.z), pkrtz(f6.z, f7.z));
        *reinterpret_cast<uint4*>(&tin[bi + (((wqs * 4 + 3) ^ sw) << 2)]) =
            make_uint4(pkrtz(f0.w, f1.w), pkrtz(f2.w, f3.w), pkrtz(f4.w, f5.w), pkrtz(f6.w, f7.w));
    }

    const int lane = tid & 63;
    const int wv   = tid >> 6;
    const int kc   = lane >> 4;
    const int arow = lane & 15;
    const int q    = arow >> 2, cp = arow & 3;
    const int cpy  = cp >> 1,  cpx = cp & 1;

    int offp[7], sw2[7];
#pragma unroll
    for (int ks = 0; ks < 7; ++ks) {
        int tap = 4 * ks + kc;
        if (tap > 24) tap = 24;        // B is zero there
        const int kd = tap / 5, kh = tap % 5;
        const int pos = (2 * wv + cpy + kd) * 12 + (2 * q + cpx + kh);
        offp[ks] = pos * 32;
        sw2[ks]  = pos & 7;
    }

    __syncthreads();

    f16x8 Bf[7];
#pragma unroll
    for (int ks = 0; ks < 7; ++ks) {
        const uint4 t = *reinterpret_cast<const uint4*>(&wl[(ks * 64 + lane) * 4]);
        Bf[ks] = __builtin_bit_cast(f16x8, t);
    }

    f32x4 acc[8];
#pragma unroll
    for (int w = 0; w < 8; ++w) acc[w] = (f32x4)(0.f);

#pragma unroll
    for (int w = 0; w < 8; ++w) {
#pragma unroll
        for (int ks = 0; ks < 7; ++ks) {
            const uint4 a4 = *reinterpret_cast<const uint4*>(
                &tin[offp[ks] + (((w ^ sw2[ks])) << 2)]);
            acc[w] = __builtin_amdgcn_mfma_f32_16x16x32_f16(
                __builtin_bit_cast(f16x8, a4), Bf[ks], acc[w], 0, 0, 0);
        }
    }

    const int oc = lane & 15, qo = lane >> 4;
    const int pi = py0 + wv, pjg = px0 + qo;   // < 28 always
    if (oc < 10) {
        const float bb = b2[oc];
        float vals[8];
#pragma unroll
        for (int w = 0; w < 8; ++w) {
            const float m = fmaxf(fmaxf(acc[w][0], acc[w][1]), fmaxf(acc[w][2], acc[w][3]));
            vals[w] = fmaxf(m + bb, 0.f);
        }
        float* base = h2 + ((((size_t)b * 10 + oc) * 28 + pi) * 28 + pjg) * 8;
        *reinterpret_cast<float4*>(base)     = make_float4(vals[0], vals[1], vals[2], vals[3]);
        *reinterpret_cast<float4*>(base + 4) = make_float4(vals[4], vals[5], vals[6], vals[7]);
    }
}

// ---------------- K3: fc1 (62720 -> 32), chunk-per-block: feat staged ONCE ----------
// grid 160 blocks; chunk = 392 floats. 256 thr = 32 j x 8 b.
// partials[(j*160 + blk)*8 + b].
__global__ __launch_bounds__(256) void k_fc1(const float* __restrict__ feat,
                                             const float* __restrict__ w,
                                             float* __restrict__ partials) {
    const int blk = blockIdx.x;
    const int tid = threadIdx.x;

    __shared__ float sf[8 * 392];      // [b][392]

    // stage feat chunk: 784 float4 (98 per b)
    const float4* f4g = reinterpret_cast<const float4*>(feat);
    for (int s = tid; s < 784; s += 256) {
        const int b = s / 98, i = s % 98;
        *reinterpret_cast<float4*>(&sf[(b * 98 + i) * 4]) =
            f4g[(size_t)b * 15680 + blk * 98 + i];
    }
    __syncthreads();

    const int j = tid >> 3, b = tid & 7;
    const float4* wp = reinterpret_cast<const float4*>(w) + (size_t)j * 15680 + blk * 98;
    const float4* fp = reinterpret_cast<const float4*>(&sf[b * 392]);
    float acc = 0.f;
#pragma unroll 7
    for (int i = 0; i < 98; ++i) {
        const float4 wv = wp[i];
        const float4 fv = fp[i];
        acc = fmaf(wv.x, fv.x, fmaf(wv.y, fv.y, fmaf(wv.z, fv.z, fmaf(wv.w, fv.w, acc))));
    }
    partials[(j * 160 + blk) * 8 + b] = acc;
}

// ---------------- K4: fc1-reduce + fc2 + rigid (in-block) + flow + sample + moved ------
__global__ __launch_bounds__(256) void k_flow_all(const float* __restrict__ x,
                                                  const float* __restrict__ partials,
                                                  const float* __restrict__ f1b,
                                                  const float* __restrict__ f2w,
                                                  const float* __restrict__ f2b,
                                                  const float* __restrict__ pos,
                                                  const float* __restrict__ centers,
                                                  float* __restrict__ outXt,
                                                  float* __restrict__ outGrid,
                                                  float* __restrict__ movedOut,
                                                  float* __restrict__ regOut) {
    const int b = blockIdx.y;
    const int tid = threadIdx.x;
    const int l = blockIdx.x * 256 + tid;

    __shared__ float sfo[32];
    __shared__ float srt[64];
    __shared__ float sg[768];
    __shared__ float red[128];

    if (tid < 32) {
        float s = 0.f;
        for (int kc = 0; kc < 160; ++kc) s += partials[(tid * 160 + kc) * 8 + b];
        sfo[tid] = fmaxf(s + f1b[tid], 0.f);
    }
    __syncthreads();
    if (tid < 8) {
        const int t = tid;
        float th[6];
#pragma unroll
        for (int i = 0; i < 6; ++i) {
            const int o = t * 6 + i;
            float s = f2b[o];
            const float* wr = f2w + o * 32;
#pragma unroll
            for (int k = 0; k < 32; ++k) s = fmaf(sfo[k], wr[k], s);
            th[i] = tanhf(s);
        }
        float s0, c0, s1, c1, s2, c2;
        sincosf(PI_F * th[0], &s0, &c0);
        sincosf(PI_F * th[1], &s1, &c1);
        sincosf(PI_F * th[2], &s2, &c2);
        const float R00 = c0 * c1, R10 = s0 * c1, R20 = -s1;
        const float R01 = -s0 * c2 + c0 * s1 * s2;
        const float R11 =  c0 * c2 + s0 * s1 * s2;
        const float R21 =  c1 * s2;
        const float T0 = th[3] * 128.f + 64.f - (64.f * R00 + 64.f * R10 + 4.f * R20);
        const float T1 = th[4] * 128.f + 64.f - (64.f * R01 + 64.f * R11 + 4.f * R21);
        float* o = srt + t * 8;
        o[0] = R00; o[1] = R10; o[2] = R20; o[3] = T0;
        o[4] = R01; o[5] = R11; o[6] = R21; o[7] = T1;
    }
    __syncthreads();

    const float gi = (float)(l >> 10);
    const float gj = (float)((l >> 3) & 127);
    const float gk = (float)(l & 7);

    const float tsx[8] = {32.f, 32.f, 96.f, 96.f, 32.f, 96.f, 64.f, 64.f};
    const float tsy[8] = {32.f, 96.f, 32.f, 96.f, 64.f, 64.f, 32.f, 96.f};

    float u0 = 0.f, u1 = 0.f, es = 0.f;
#pragma unroll
    for (int t = 0; t < 8; ++t) {
        float dx = gi - tsx[t], dy = gj - tsy[t], dz = gk - 4.f;
        float d = sqrtf(dx * dx + dy * dy + dz * dz);
        float e = expf(-d / 10.f);
        const float4 ra = *reinterpret_cast<const float4*>(&srt[t * 8]);
        const float4 rb = *reinterpret_cast<const float4*>(&srt[t * 8 + 4]);
        float f0 = fmaf(gi, ra.x, fmaf(gj, ra.y, fmaf(gk, ra.z, ra.w)));
        float f1 = fmaf(gi, rb.x, fmaf(gj, rb.y, fmaf(gk, rb.z, rb.w)));
        u0 = fmaf(e, f0, u0);
        u1 = fmaf(e, f1, u1);
        es += e;
    }
    const float inv = 1.f / es;
    const float fs0 = u0 * inv, fs1 = u1 * inv;
    const float nf0 = fs0 * (1.f / 64.f) - 1.f;
    const float nf1 = fs1 * (1.f / 64.f) - 1.f;

    sg[tid * 3 + 0] = 0.f;
    sg[tid * 3 + 1] = nf1;
    sg[tid * 3 + 2] = nf0;
    __syncthreads();
    if (tid < 192) {
        *reinterpret_cast<float4*>(outGrid + (size_t)b * 393216 + (size_t)blockIdx.x * 768 +
                                   tid * 4) = *reinterpret_cast<float4*>(&sg[tid * 4]);
    }

    const float iz = fs0 - 0.5f, iy = fs1 - 0.5f;
    const float z0f = floorf(iz), y0f = floorf(iy);
    const float fz = iz - z0f, fy = iy - y0f;
    const int z0 = (int)z0f, y0 = (int)y0f;
    float s0 = 0.f, s1 = 0.f, s2 = 0.f, s3 = 0.f;
    const float* xb = x + (size_t)b * 4 * 131072;
#pragma unroll
    for (int dz = 0; dz < 2; ++dz) {
        const int zc = z0 + dz;
        if (zc < 0 || zc > 127) continue;
        const float wz = dz ? fz : 1.f - fz;
#pragma unroll
        for (int dy = 0; dy < 2; ++dy) {
            const int yc = y0 + dy;
            if (yc < 0 || yc > 127) continue;
            const float wv = wz * (dy ? fy : 1.f - fy) * 0.5f;
            const float* p = xb + ((size_t)zc * 128 + yc) * 8 + 3;
            s0 = fmaf(wv, p[0] + p[1], s0);
            s1 = fmaf(wv, p[131072] + p[131073], s1);
            s2 = fmaf(wv, p[262144] + p[262145], s2);
            s3 = fmaf(wv, p[393216] + p[393217], s3);
        }
    }
    float* o = outXt + (size_t)b * 4 * 131072 + l;
    o[0] = s0; o[131072] = s1; o[262144] = s2; o[393216] = s3;

    if (blockIdx.x == 0) {
        float nrm = 0.f;
        if (tid < 128) {
            const int p = tid;
            if (p < 100) {
                const float* pp = pos + ((size_t)b * 100 + p) * 3;
                const float p0 = pp[0], p1 = pp[1], p2 = pp[2];
                int i0 = (int)rintf(p0); i0 = i0 < 0 ? 0 : (i0 > 127 ? 127 : i0);
                int i1 = (int)rintf(p1); i1 = i1 < 0 ? 0 : (i1 > 127 ? 127 : i1);
                int i2 = (int)rintf(p2); i2 = i2 < 0 ? 0 : (i2 > 7 ? 7 : i2);
                const float qi = (float)i0, qj = (float)i1, qk = (float)i2;
                float v0 = 0.f, v1 = 0.f, esm = 0.f;
#pragma unroll
                for (int t = 0; t < 8; ++t) {
                    float dx = qi - tsx[t], dy = qj - tsy[t], dz = qk - 4.f;
                    float d = sqrtf(dx * dx + dy * dy + dz * dz);
                    float e = expf(-d / 10.f);
                    const float* r = srt + t * 8;
                    float f0 = fmaf(qi, r[0], fmaf(qj, r[1], fmaf(qk, r[2], r[3])));
                    float f1 = fmaf(qi, r[4], fmaf(qj, r[5], fmaf(qk, r[6], r[7])));
                    v0 = fmaf(e, f0, v0);
                    v1 = fmaf(e, f1, v1);
                    esm += e;
                }
                const float invm = 1.f / esm;
                const float m0 = 2.f * p0 - (0.5f + 0.5f * ((v0 * invm) * (1.f / 64.f) - 1.f)) * 127.f;
                const float m1 = 2.f * p1 - (0.5f + 0.5f * ((v1 * invm) * (1.f / 64.f) - 1.f)) * 127.f;
                const float m2 = 2.f * p2 - 3.5f;
                float* mo = movedOut + ((size_t)b * 100 + p) * 3;
                mo[0] = m0; mo[1] = m1; mo[2] = m2;
                const float* ce = centers + p * 3;
                const float d0 = m0 - ce[0], d1 = m1 - ce[1], d2 = m2 - ce[2];
                nrm = sqrtf(d0 * d0 + d1 * d1 + d2 * d2);
            }
            red[tid] = nrm;
        }
        __syncthreads();
        for (int s = 64; s > 0; s >>= 1) {
            if (tid < s) red[tid] += red[tid + s];
            __syncthreads();
        }
        if (tid == 0) regOut[b] = red[0] * 0.01f;
    }
}

// ---------------- launch ----------------
extern "C" void kernel_launch(void* const* d_in, const int* in_sizes, int n_in,
                              void* d_out, int out_size, void* d_ws, size_t ws_size,
                              hipStream_t stream) {
    const float* x       = (const float*)d_in[0];
    const float* pos     = (const float*)d_in[1];
    const float* centers = (const float*)d_in[2];
    const float* c1w     = (const float*)d_in[3];
    const float* c1b     = (const float*)d_in[4];
    const float* c2w     = (const float*)d_in[5];
    const float* c2b     = (const float*)d_in[6];
    const float* f1w     = (const float*)d_in[7];
    const float* f1b     = (const float*)d_in[8];
    const float* f2w     = (const float*)d_in[9];
    const float* f2b     = (const float*)d_in[10];

    float* out = (float*)d_out;
    float* ws  = (float*)d_ws;

    // workspace layout (floats)
    float* h1       = ws;                      // 8*8*61*61*8   = 1,905,152
    float* h2       = h1 + 1905152;            // 8*10*28*28*8  =   501,760
    float* partials = h2 + 501760;             // 32*160*8      =    40,960

    // output layout (floats): X_t | grid | reg | moved
    float* outXt    = out;                         // 4,194,304
    float* outGrid  = out + 4194304;               // 3,145,728
    float* outReg   = out + 4194304 + 3145728;     // 8
    float* outMoved = outReg + 8;                  // 2,400

    k_conv1<<<dim3(256, 8), 256, 0, stream>>>(x, c1w, c1b, h1);
    k_conv2<<<dim3(49, 8), 256, 0, stream>>>(h1, c2w, c2b, h2);
    k_fc1<<<160, 256, 0, stream>>>(h2, f1w, partials);
    k_flow_all<<<dim3(512, 8), 256, 0, stream>>>(x, partials, f1b, f2w, f2b, pos, centers,
                                                 outXt, outGrid, outMoved, outReg);
}

// Round 17
// 66.433 us; speedup vs baseline: 1.5645x; 1.5645x over previous
//
#include <hip/hip_runtime.h>

#define PI_F 3.14159265358979323846f

typedef _Float16 h2t __attribute__((ext_vector_type(2)));
typedef __fp16 fp16x2 __attribute__((ext_vector_type(2)));
typedef _Float16 f16x8 __attribute__((ext_vector_type(8)));
typedef float f32x4 __attribute__((ext_vector_type(4)));
typedef unsigned int uint32;

__device__ __forceinline__ uint32 packh(float a, float b) {   // RNE
    h2t h = {(_Float16)a, (_Float16)b};
    return __builtin_bit_cast(uint32, h);
}
__device__ __forceinline__ uint32 pkrtz(float a, float b) {   // fast, staging
    fp16x2 h = __builtin_amdgcn_cvt_pkrtz(a, b);
    return __builtin_bit_cast(uint32, h);
}

// ---------------- K1: conv1 via MFMA 16x16x32_f16, XOR-swizzled LDS ----------------
__global__ __launch_bounds__(256) void k_conv1(const float* __restrict__ x,
                                               const float* __restrict__ w1,
                                               const float* __restrict__ b1,
                                               float* __restrict__ h1) {
    const int b = blockIdx.y;
    const int ty = blockIdx.x >> 4, tx = blockIdx.x & 15;   // 16 x 16 tiles
    const int py0 = ty * 4, px0 = tx * 4;
    const int iy0 = py0 * 2, ix0 = px0 * 2;

    __shared__ uint32 tin[14 * 15 * 16];
    __shared__ uint32 wl[1792];

    const int tid = threadIdx.x;

    for (int i = tid; i < 1792; i += 256) {
        const int idx4 = i >> 2, rem = i & 3;
        const int h = rem >> 1, icp = rem & 1;
        const int oc = idx4 & 15, kcg = idx4 >> 4;
        const int ks = kcg >> 2, c = kcg & 3;
        const int tap = 8 * ks + c + 4 * h;
        uint32 v = 0;
        if (tap < 49 && oc < 8)
            v = packh(w1[(oc * 4 + 2 * icp) * 49 + tap],
                      w1[(oc * 4 + 2 * icp + 1) * 49 + tap]);
        wl[i] = v;
    }

    const float* xb = x + (size_t)b * 4 * 131072;
    for (int s = tid; s < 392; s += 256) {
        const int r = s / 28, rem = s % 28, c = rem >> 1, wqs = rem & 1;
        const int row = min(iy0 + r, 127), col = min(ix0 + c, 127);
        const float* base = xb + ((size_t)row * 128 + col) * 8 + wqs * 4;
        const float4 f0 = *reinterpret_cast<const float4*>(base);
        const float4 f1 = *reinterpret_cast<const float4*>(base + 131072);
        const float4 f2 = *reinterpret_cast<const float4*>(base + 262144);
        const float4 f3 = *reinterpret_cast<const float4*>(base + 393216);
        const int pos = r * 15 + c;
        const int sw = pos & 7;
        const int bi = pos * 16;
        *reinterpret_cast<uint2*>(&tin[bi + (((wqs * 4 + 0) ^ sw) << 1)]) =
            make_uint2(pkrtz(f0.x, f1.x), pkrtz(f2.x, f3.x));
        *reinterpret_cast<uint2*>(&tin[bi + (((wqs * 4 + 1) ^ sw) << 1)]) =
            make_uint2(pkrtz(f0.y, f1.y), pkrtz(f2.y, f3.y));
        *reinterpret_cast<uint2*>(&tin[bi + (((wqs * 4 + 2) ^ sw) << 1)]) =
            make_uint2(pkrtz(f0.z, f1.z), pkrtz(f2.z, f3.z));
        *reinterpret_cast<uint2*>(&tin[bi + (((wqs * 4 + 3) ^ sw) << 1)]) =
            make_uint2(pkrtz(f0.w, f1.w), pkrtz(f2.w, f3.w));
    }

    const int lane = tid & 63;
    const int wv   = tid >> 6;
    const int kc   = lane >> 4;
    const int arow = lane & 15;
    const int q    = arow >> 2, cp = arow & 3;
    const int cpy  = cp >> 1,  cpx = cp & 1;

    int offp[7][2], sw1[7][2];
#pragma unroll
    for (int ks = 0; ks < 7; ++ks) {
#pragma unroll
        for (int h = 0; h < 2; ++h) {
            int tap = 8 * ks + kc + 4 * h;
            if (tap > 48) tap = 48;
            const int kd = tap / 7, kh = tap % 7;
            const int pos = (2 * wv + cpy + kd) * 15 + (2 * q + cpx + kh);
            offp[ks][h] = pos * 16;
            sw1[ks][h]  = pos & 7;
        }
    }

    __syncthreads();

    f16x8 Bf[7];
#pragma unroll
    for (int ks = 0; ks < 7; ++ks) {
        const uint4 t = *reinterpret_cast<const uint4*>(&wl[(ks * 64 + lane) * 4]);
        Bf[ks] = __builtin_bit_cast(f16x8, t);
    }

    f32x4 acc[8];
#pragma unroll
    for (int w = 0; w < 8; ++w) acc[w] = (f32x4)(0.f);

#pragma unroll
    for (int w = 0; w < 8; ++w) {
#pragma unroll
        for (int ks = 0; ks < 7; ++ks) {
            const uint2 lo = *reinterpret_cast<const uint2*>(
                &tin[offp[ks][0] + (((w ^ sw1[ks][0])) << 1)]);
            const uint2 hi = *reinterpret_cast<const uint2*>(
                &tin[offp[ks][1] + (((w ^ sw1[ks][1])) << 1)]);
            const uint4 a4 = make_uint4(lo.x, lo.y, hi.x, hi.y);
            acc[w] = __builtin_amdgcn_mfma_f32_16x16x32_f16(
                __builtin_bit_cast(f16x8, a4), Bf[ks], acc[w], 0, 0, 0);
        }
    }

    const int oc = lane & 15, qo = lane >> 4;
    const int pi = py0 + wv, pjg = px0 + qo;
    if (oc < 8 && pi < 61 && pjg < 61) {
        const float bb = b1[oc];
        float vals[8];
#pragma unroll
        for (int w = 0; w < 8; ++w) {
            const float m = fmaxf(fmaxf(acc[w][0], acc[w][1]), fmaxf(acc[w][2], acc[w][3]));
            vals[w] = fmaxf(m + bb, 0.f);
        }
        float* base = h1 + ((((size_t)b * 8 + oc) * 61 + pi) * 61 + pjg) * 8;
        *reinterpret_cast<float4*>(base)     = make_float4(vals[0], vals[1], vals[2], vals[3]);
        *reinterpret_cast<float4*>(base + 4) = make_float4(vals[4], vals[5], vals[6], vals[7]);
    }
}

// ---------------- K2: conv2 via MFMA 16x16x32_f16, XOR-swizzled LDS ----------------
__global__ __launch_bounds__(256) void k_conv2(const float* __restrict__ h1,
                                               const float* __restrict__ w2,
                                               const float* __restrict__ b2,
                                               float* __restrict__ h2) {
    const int b = blockIdx.y;
    const int ty = blockIdx.x / 7, tx = blockIdx.x % 7;    // 7 x 7 tiles of 4x4 pooled
    const int py0 = ty * 4, px0 = tx * 4;
    const int iy0 = py0 * 2, ix0 = px0 * 2;

    __shared__ uint32 tin[12 * 12 * 32];
    __shared__ uint32 wl[1792];

    const int tid = threadIdx.x;

    for (int i = tid; i < 1792; i += 256) {
        const int idx4 = i >> 2, d = i & 3;
        const int oc = idx4 & 15, kcg = idx4 >> 4;
        const int ks = kcg >> 2, c = kcg & 3;
        const int tap = 4 * ks + c;
        uint32 v = 0;
        if (tap < 25 && oc < 10)
            v = packh(w2[(oc * 8 + 2 * d) * 25 + tap],
                      w2[(oc * 8 + 2 * d + 1) * 25 + tap]);
        wl[i] = v;
    }

    const float* hb = h1 + (size_t)b * 8 * 29768;
    for (int s = tid; s < 288; s += 256) {
        const int pos = s >> 1, wqs = s & 1;
        const int r = pos / 12, c = pos % 12;
        const float* base = hb + ((size_t)(iy0 + r) * 61 + ix0 + c) * 8 + wqs * 4;
        const float4 f0 = *reinterpret_cast<const float4*>(base);
        const float4 f1 = *reinterpret_cast<const float4*>(base + 29768);
        const float4 f2 = *reinterpret_cast<const float4*>(base + 2 * 29768);
        const float4 f3 = *reinterpret_cast<const float4*>(base + 3 * 29768);
        const float4 f4 = *reinterpret_cast<const float4*>(base + 4 * 29768);
        const float4 f5 = *reinterpret_cast<const float4*>(base + 5 * 29768);
        const float4 f6 = *reinterpret_cast<const float4*>(base + 6 * 29768);
        const float4 f7 = *reinterpret_cast<const float4*>(base + 7 * 29768);
        const int sw = pos & 7;
        const int bi = pos * 32;
        *reinterpret_cast<uint4*>(&tin[bi + (((wqs * 4 + 0) ^ sw) << 2)]) =
            make_uint4(pkrtz(f0.x, f1.x), pkrtz(f2.x, f3.x), pkrtz(f4.x, f5.x), pkrtz(f6.x, f7.x));
        *reinterpret_cast<uint4*>(&tin[bi + (((wqs * 4 + 1) ^ sw) << 2)]) =
            make_uint4(pkrtz(f0.y, f1.y), pkrtz(f2.y, f3.y), pkrtz(f4.y, f5.y), pkrtz(f6.y, f7.y));
        *reinterpret_cast<uint4*>(&tin[bi + (((wqs * 4 + 2) ^ sw) << 2)]) =
            make_uint4(pkrtz(f0.z, f1.z), pkrtz(f2.z, f3.z), pkrtz(f4.z, f5.z), pkrtz(f6.z, f7.z));
        *reinterpret_cast<uint4*>(&tin[bi + (((wqs * 4 + 3) ^ sw) << 2)]) =
            make_uint4(pkrtz(f0.w, f1.w), pkrtz(f2.w, f3.w), pkrtz(f4.w, f5.w), pkrtz(f6.w, f7.w));
    }

    const int lane = tid & 63;
    const int wv   = tid >> 6;
    const int kc   = lane >> 4;
    const int arow = lane & 15;
    const int q    = arow >> 2, cp = arow & 3;
    const int cpy  = cp >> 1,  cpx = cp & 1;

    int offp[7], sw2[7];
#pragma unroll
    for (int ks = 0; ks < 7; ++ks) {
        int tap = 4 * ks + kc;
        if (tap > 24) tap = 24;
        const int kd = tap / 5, kh = tap % 5;
        const int pos = (2 * wv + cpy + kd) * 12 + (2 * q + cpx + kh);
        offp[ks] = pos * 32;
        sw2[ks]  = pos & 7;
    }

    __syncthreads();

    f16x8 Bf[7];
#pragma unroll
    for (int ks = 0; ks < 7; ++ks) {
        const uint4 t = *reinterpret_cast<const uint4*>(&wl[(ks * 64 + lane) * 4]);
        Bf[ks] = __builtin_bit_cast(f16x8, t);
    }

    f32x4 acc[8];
#pragma unroll
    for (int w = 0; w < 8; ++w) acc[w] = (f32x4)(0.f);

#pragma unroll
    for (int w = 0; w < 8; ++w) {
#pragma unroll
        for (int ks = 0; ks < 7; ++ks) {
            const uint4 a4 = *reinterpret_cast<const uint4*>(
                &tin[offp[ks] + (((w ^ sw2[ks])) << 2)]);
            acc[w] = __builtin_amdgcn_mfma_f32_16x16x32_f16(
                __builtin_bit_cast(f16x8, a4), Bf[ks], acc[w], 0, 0, 0);
        }
    }

    const int oc = lane & 15, qo = lane >> 4;
    const int pi = py0 + wv, pjg = px0 + qo;
    if (oc < 10) {
        const float bb = b2[oc];
        float vals[8];
#pragma unroll
        for (int w = 0; w < 8; ++w) {
            const float m = fmaxf(fmaxf(acc[w][0], acc[w][1]), fmaxf(acc[w][2], acc[w][3]));
            vals[w] = fmaxf(m + bb, 0.f);
        }
        float* base = h2 + ((((size_t)b * 10 + oc) * 28 + pi) * 28 + pjg) * 8;
        *reinterpret_cast<float4*>(base)     = make_float4(vals[0], vals[1], vals[2], vals[3]);
        *reinterpret_cast<float4*>(base + 4) = make_float4(vals[4], vals[5], vals[6], vals[7]);
    }
}

// ---------------- K3: fc1 (62720 -> 32), chunk-per-block: feat staged ONCE ----------
__global__ __launch_bounds__(256) void k_fc1(const float* __restrict__ feat,
                                             const float* __restrict__ w,
                                             float* __restrict__ partials) {
    const int blk = blockIdx.x;
    const int tid = threadIdx.x;

    __shared__ float sf[8 * 392];

    const float4* f4g = reinterpret_cast<const float4*>(feat);
    for (int s = tid; s < 784; s += 256) {
        const int b = s / 98, i = s % 98;
        *reinterpret_cast<float4*>(&sf[(b * 98 + i) * 4]) =
            f4g[(size_t)b * 15680 + blk * 98 + i];
    }
    __syncthreads();

    const int j = tid >> 3, b = tid & 7;
    const float4* wp = reinterpret_cast<const float4*>(w) + (size_t)j * 15680 + blk * 98;
    const float4* fp = reinterpret_cast<const float4*>(&sf[b * 392]);
    float acc = 0.f;
#pragma unroll 7
    for (int i = 0; i < 98; ++i) {
        const float4 wv = wp[i];
        const float4 fv = fp[i];
        acc = fmaf(wv.x, fv.x, fmaf(wv.y, fv.y, fmaf(wv.z, fv.z, fmaf(wv.w, fv.w, acc))));
    }
    partials[(j * 160 + blk) * 8 + b] = acc;
}

// ---------------- K3b: reduce partials + fc2 + tanh + rigid -> rt[64] ----------------
// 1 block, 256 threads: thread = (j,b) sums its 160 partials -> sfo; 64 threads do rt.
__global__ __launch_bounds__(256) void k_rt(const float* __restrict__ partials,
                                            const float* __restrict__ f1b,
                                            const float* __restrict__ f2w,
                                            const float* __restrict__ f2b,
                                            float* __restrict__ rt) {
    const int tid = threadIdx.x;
    __shared__ float sfo[256];         // [b][j]

    {
        const int j = tid >> 3, b = tid & 7;
        const float* p = partials + (size_t)j * 160 * 8 + b;
        float s = 0.f;
        for (int kc = 0; kc < 160; ++kc) s += p[kc * 8];
        sfo[b * 32 + j] = fmaxf(s + f1b[j], 0.f);
    }
    __syncthreads();
    if (tid < 64) {
        const int b = tid >> 3, t = tid & 7;
        const float* f = &sfo[b * 32];
        float th[6];
#pragma unroll
        for (int i = 0; i < 6; ++i) {
            const int o = t * 6 + i;
            float s = f2b[o];
            const float* wr = f2w + o * 32;
#pragma unroll
            for (int k = 0; k < 32; ++k) s = fmaf(f[k], wr[k], s);
            th[i] = tanhf(s);
        }
        float s0, c0, s1, c1, s2, c2;
        sincosf(PI_F * th[0], &s0, &c0);
        sincosf(PI_F * th[1], &s1, &c1);
        sincosf(PI_F * th[2], &s2, &c2);
        const float R00 = c0 * c1, R10 = s0 * c1, R20 = -s1;
        const float R01 = -s0 * c2 + c0 * s1 * s2;
        const float R11 =  c0 * c2 + s0 * s1 * s2;
        const float R21 =  c1 * s2;
        const float T0 = th[3] * 128.f + 64.f - (64.f * R00 + 64.f * R10 + 4.f * R20);
        const float T1 = th[4] * 128.f + 64.f - (64.f * R01 + 64.f * R11 + 4.f * R21);
        float* o = rt + tid * 8;
        o[0] = R00; o[1] = R10; o[2] = R20; o[3] = T0;
        o[4] = R01; o[5] = R11; o[6] = R21; o[7] = T1;
    }
}

// ---------------- K4: flow + grid + trilinear sample + moved/reg (rt from global) ------
__global__ __launch_bounds__(256) void k_flow_all(const float* __restrict__ x,
                                                  const float* __restrict__ rt,
                                                  const float* __restrict__ pos,
                                                  const float* __restrict__ centers,
                                                  float* __restrict__ outXt,
                                                  float* __restrict__ outGrid,
                                                  float* __restrict__ movedOut,
                                                  float* __restrict__ regOut) {
    const int b = blockIdx.y;
    const int tid = threadIdx.x;
    const int l = blockIdx.x * 256 + tid;

    __shared__ float srt[64];
    __shared__ float sg[768];
    __shared__ float red[128];

    if (tid < 64) srt[tid] = rt[b * 64 + tid];
    __syncthreads();

    const float gi = (float)(l >> 10);
    const float gj = (float)((l >> 3) & 127);
    const float gk = (float)(l & 7);

    const float tsx[8] = {32.f, 32.f, 96.f, 96.f, 32.f, 96.f, 64.f, 64.f};
    const float tsy[8] = {32.f, 96.f, 32.f, 96.f, 64.f, 64.f, 32.f, 96.f};

    float u0 = 0.f, u1 = 0.f, es = 0.f;
#pragma unroll
    for (int t = 0; t < 8; ++t) {
        float dx = gi - tsx[t], dy = gj - tsy[t], dz = gk - 4.f;
        float d = sqrtf(dx * dx + dy * dy + dz * dz);
        float e = expf(-d / 10.f);
        const float4 ra = *reinterpret_cast<const float4*>(&srt[t * 8]);
        const float4 rb = *reinterpret_cast<const float4*>(&srt[t * 8 + 4]);
        float f0 = fmaf(gi, ra.x, fmaf(gj, ra.y, fmaf(gk, ra.z, ra.w)));
        float f1 = fmaf(gi, rb.x, fmaf(gj, rb.y, fmaf(gk, rb.z, rb.w)));
        u0 = fmaf(e, f0, u0);
        u1 = fmaf(e, f1, u1);
        es += e;
    }
    const float inv = 1.f / es;
    const float fs0 = u0 * inv, fs1 = u1 * inv;
    const float nf0 = fs0 * (1.f / 64.f) - 1.f;
    const float nf1 = fs1 * (1.f / 64.f) - 1.f;

    sg[tid * 3 + 0] = 0.f;
    sg[tid * 3 + 1] = nf1;
    sg[tid * 3 + 2] = nf0;
    __syncthreads();
    if (tid < 192) {
        *reinterpret_cast<float4*>(outGrid + (size_t)b * 393216 + (size_t)blockIdx.x * 768 +
                                   tid * 4) = *reinterpret_cast<float4*>(&sg[tid * 4]);
    }

    const float iz = fs0 - 0.5f, iy = fs1 - 0.5f;
    const float z0f = floorf(iz), y0f = floorf(iy);
    const float fz = iz - z0f, fy = iy - y0f;
    const int z0 = (int)z0f, y0 = (int)y0f;
    float s0 = 0.f, s1 = 0.f, s2 = 0.f, s3 = 0.f;
    const float* xb = x + (size_t)b * 4 * 131072;
#pragma unroll
    for (int dz = 0; dz < 2; ++dz) {
        const int zc = z0 + dz;
        if (zc < 0 || zc > 127) continue;
        const float wz = dz ? fz : 1.f - fz;
#pragma unroll
        for (int dy = 0; dy < 2; ++dy) {
            const int yc = y0 + dy;
            if (yc < 0 || yc > 127) continue;
            const float wv = wz * (dy ? fy : 1.f - fy) * 0.5f;
            const float* p = xb + ((size_t)zc * 128 + yc) * 8 + 3;
            s0 = fmaf(wv, p[0] + p[1], s0);
            s1 = fmaf(wv, p[131072] + p[131073], s1);
            s2 = fmaf(wv, p[262144] + p[262145], s2);
            s3 = fmaf(wv, p[393216] + p[393217], s3);
        }
    }
    float* o = outXt + (size_t)b * 4 * 131072 + l;
    o[0] = s0; o[131072] = s1; o[262144] = s2; o[393216] = s3;

    if (blockIdx.x == 0) {
        float nrm = 0.f;
        if (tid < 128) {
            const int p = tid;
            if (p < 100) {
                const float* pp = pos + ((size_t)b * 100 + p) * 3;
                const float p0 = pp[0], p1 = pp[1], p2 = pp[2];
                int i0 = (int)rintf(p0); i0 = i0 < 0 ? 0 : (i0 > 127 ? 127 : i0);
                int i1 = (int)rintf(p1); i1 = i1 < 0 ? 0 : (i1 > 127 ? 127 : i1);
                int i2 = (int)rintf(p2); i2 = i2 < 0 ? 0 : (i2 > 7 ? 7 : i2);
                const float qi = (float)i0, qj = (float)i1, qk = (float)i2;
                float v0 = 0.f, v1 = 0.f, esm = 0.f;
#pragma unroll
                for (int t = 0; t < 8; ++t) {
                    float dx = qi - tsx[t], dy = qj - tsy[t], dz = qk - 4.f;
                    float d = sqrtf(dx * dx + dy * dy + dz * dz);
                    float e = expf(-d / 10.f);
                    const float* r = srt + t * 8;
                    float f0 = fmaf(qi, r[0], fmaf(qj, r[1], fmaf(qk, r[2], r[3])));
                    float f1 = fmaf(qi, r[4], fmaf(qj, r[5], fmaf(qk, r[6], r[7])));
                    v0 = fmaf(e, f0, v0);
                    v1 = fmaf(e, f1, v1);
                    esm += e;
                }
                const float invm = 1.f / esm;
                const float m0 = 2.f * p0 - (0.5f + 0.5f * ((v0 * invm) * (1.f / 64.f) - 1.f)) * 127.f;
                const float m1 = 2.f * p1 - (0.5f + 0.5f * ((v1 * invm) * (1.f / 64.f) - 1.f)) * 127.f;
                const float m2 = 2.f * p2 - 3.5f;
                float* mo = movedOut + ((size_t)b * 100 + p) * 3;
                mo[0] = m0; mo[1] = m1; mo[2] = m2;
                const float* ce = centers + p * 3;
                const float d0 = m0 - ce[0], d1 = m1 - ce[1], d2 = m2 - ce[2];
                nrm = sqrtf(d0 * d0 + d1 * d1 + d2 * d2);
            }
            red[tid] = nrm;
        }
        __syncthreads();
        for (int s = 64; s > 0; s >>= 1) {
            if (tid < s) red[tid] += red[tid + s];
            __syncthreads();
        }
        if (tid == 0) regOut[b] = red[0] * 0.01f;
    }
}

// ---------------- launch ----------------
extern "C" void kernel_launch(void* const* d_in, const int* in_sizes, int n_in,
                              void* d_out, int out_size, void* d_ws, size_t ws_size,
                              hipStream_t stream) {
    const float* x       = (const float*)d_in[0];
    const float* pos     = (const float*)d_in[1];
    const float* centers = (const float*)d_in[2];
    const float* c1w     = (const float*)d_in[3];
    const float* c1b     = (const float*)d_in[4];
    const float* c2w     = (const float*)d_in[5];
    const float* c2b     = (const float*)d_in[6];
    const float* f1w     = (const float*)d_in[7];
    const float* f1b     = (const float*)d_in[8];
    const float* f2w     = (const float*)d_in[9];
    const float* f2b     = (const float*)d_in[10];

    float* out = (float*)d_out;
    float* ws  = (float*)d_ws;

    // workspace layout (floats)
    float* h1       = ws;                      // 8*8*61*61*8   = 1,905,152
    float* h2       = h1 + 1905152;            // 8*10*28*28*8  =   501,760
    float* partials = h2 + 501760;             // 32*160*8      =    40,960
    float* rt       = partials + 40960;        // 64*8          =       512

    // output layout (floats): X_t | grid | reg | moved
    float* outXt    = out;                         // 4,194,304
    float* outGrid  = out + 4194304;               // 3,145,728
    float* outReg   = out + 4194304 + 3145728;     // 8
    float* outMoved = outReg + 8;                  // 2,400

    k_conv1<<<dim3(256, 8), 256, 0, stream>>>(x, c1w, c1b, h1);
    k_conv2<<<dim3(49, 8), 256, 0, stream>>>(h1, c2w, c2b, h2);
    k_fc1<<<160, 256, 0, stream>>>(h2, f1w, partials);
    k_rt<<<1, 256, 0, stream>>>(partials, f1b, f2w, f2b, rt);
    k_flow_all<<<dim3(512, 8), 256, 0, stream>>>(x, rt, pos, centers,
                                                 outXt, outGrid, outMoved, outReg);
}

// Round 19
// 66.143 us; speedup vs baseline: 1.5714x; 1.0044x over previous
//
#include <hip/hip_runtime.h>

#define PI_F 3.14159265358979323846f

typedef _Float16 h2t __attribute__((ext_vector_type(2)));
typedef __fp16 fp16x2 __attribute__((ext_vector_type(2)));
typedef _Float16 f16x8 __attribute__((ext_vector_type(8)));
typedef float f32x4 __attribute__((ext_vector_type(4)));
typedef unsigned int uint32;

__device__ __forceinline__ uint32 packh(float a, float b) {   // RNE
    h2t h = {(_Float16)a, (_Float16)b};
    return __builtin_bit_cast(uint32, h);
}
__device__ __forceinline__ uint32 pkrtz(float a, float b) {   // fast, staging
    fp16x2 h = __builtin_amdgcn_cvt_pkrtz(a, b);
    return __builtin_bit_cast(uint32, h);
}

// ---------------- K1: conv1 via MFMA 16x16x32_f16, XOR-swizzled LDS ----------------
__global__ __launch_bounds__(256) void k_conv1(const float* __restrict__ x,
                                               const float* __restrict__ w1,
                                               const float* __restrict__ b1,
                                               float* __restrict__ h1) {
    const int b = blockIdx.y;
    const int ty = blockIdx.x >> 4, tx = blockIdx.x & 15;   // 16 x 16 tiles
    const int py0 = ty * 4, px0 = tx * 4;
    const int iy0 = py0 * 2, ix0 = px0 * 2;

    __shared__ uint32 tin[14 * 15 * 16];
    __shared__ uint32 wl[1792];

    const int tid = threadIdx.x;

    for (int i = tid; i < 1792; i += 256) {
        const int idx4 = i >> 2, rem = i & 3;
        const int h = rem >> 1, icp = rem & 1;
        const int oc = idx4 & 15, kcg = idx4 >> 4;
        const int ks = kcg >> 2, c = kcg & 3;
        const int tap = 8 * ks + c + 4 * h;
        uint32 v = 0;
        if (tap < 49 && oc < 8)
            v = packh(w1[(oc * 4 + 2 * icp) * 49 + tap],
                      w1[(oc * 4 + 2 * icp + 1) * 49 + tap]);
        wl[i] = v;
    }

    const float* xb = x + (size_t)b * 4 * 131072;
    for (int s = tid; s < 392; s += 256) {
        const int r = s / 28, rem = s % 28, c = rem >> 1, wqs = rem & 1;
        const int row = min(iy0 + r, 127), col = min(ix0 + c, 127);
        const float* base = xb + ((size_t)row * 128 + col) * 8 + wqs * 4;
        const float4 f0 = *reinterpret_cast<const float4*>(base);
        const float4 f1 = *reinterpret_cast<const float4*>(base + 131072);
        const float4 f2 = *reinterpret_cast<const float4*>(base + 262144);
        const float4 f3 = *reinterpret_cast<const float4*>(base + 393216);
        const int pos = r * 15 + c;
        const int sw = pos & 7;
        const int bi = pos * 16;
        *reinterpret_cast<uint2*>(&tin[bi + (((wqs * 4 + 0) ^ sw) << 1)]) =
            make_uint2(pkrtz(f0.x, f1.x), pkrtz(f2.x, f3.x));
        *reinterpret_cast<uint2*>(&tin[bi + (((wqs * 4 + 1) ^ sw) << 1)]) =
            make_uint2(pkrtz(f0.y, f1.y), pkrtz(f2.y, f3.y));
        *reinterpret_cast<uint2*>(&tin[bi + (((wqs * 4 + 2) ^ sw) << 1)]) =
            make_uint2(pkrtz(f0.z, f1.z), pkrtz(f2.z, f3.z));
        *reinterpret_cast<uint2*>(&tin[bi + (((wqs * 4 + 3) ^ sw) << 1)]) =
            make_uint2(pkrtz(f0.w, f1.w), pkrtz(f2.w, f3.w));
    }

    const int lane = tid & 63;
    const int wv   = tid >> 6;
    const int kc   = lane >> 4;
    const int arow = lane & 15;
    const int q    = arow >> 2, cp = arow & 3;
    const int cpy  = cp >> 1,  cpx = cp & 1;

    int offp[7][2], sw1[7][2];
#pragma unroll
    for (int ks = 0; ks < 7; ++ks) {
#pragma unroll
        for (int h = 0; h < 2; ++h) {
            int tap = 8 * ks + kc + 4 * h;
            if (tap > 48) tap = 48;
            const int kd = tap / 7, kh = tap % 7;
            const int pos = (2 * wv + cpy + kd) * 15 + (2 * q + cpx + kh);
            offp[ks][h] = pos * 16;
            sw1[ks][h]  = pos & 7;
        }
    }

    __syncthreads();

    f16x8 Bf[7];
#pragma unroll
    for (int ks = 0; ks < 7; ++ks) {
        const uint4 t = *reinterpret_cast<const uint4*>(&wl[(ks * 64 + lane) * 4]);
        Bf[ks] = __builtin_bit_cast(f16x8, t);
    }

    f32x4 acc[8];
#pragma unroll
    for (int w = 0; w < 8; ++w) acc[w] = (f32x4)(0.f);

#pragma unroll
    for (int w = 0; w < 8; ++w) {
#pragma unroll
        for (int ks = 0; ks < 7; ++ks) {
            const uint2 lo = *reinterpret_cast<const uint2*>(
                &tin[offp[ks][0] + (((w ^ sw1[ks][0])) << 1)]);
            const uint2 hi = *reinterpret_cast<const uint2*>(
                &tin[offp[ks][1] + (((w ^ sw1[ks][1])) << 1)]);
            const uint4 a4 = make_uint4(lo.x, lo.y, hi.x, hi.y);
            acc[w] = __builtin_amdgcn_mfma_f32_16x16x32_f16(
                __builtin_bit_cast(f16x8, a4), Bf[ks], acc[w], 0, 0, 0);
        }
    }

    const int oc = lane & 15, qo = lane >> 4;
    const int pi = py0 + wv, pjg = px0 + qo;
    if (oc < 8 && pi < 61 && pjg < 61) {
        const float bb = b1[oc];
        float vals[8];
#pragma unroll
        for (int w = 0; w < 8; ++w) {
            const float m = fmaxf(fmaxf(acc[w][0], acc[w][1]), fmaxf(acc[w][2], acc[w][3]));
            vals[w] = fmaxf(m + bb, 0.f);
        }
        float* base = h1 + ((((size_t)b * 8 + oc) * 61 + pi) * 61 + pjg) * 8;
        *reinterpret_cast<float4*>(base)     = make_float4(vals[0], vals[1], vals[2], vals[3]);
        *reinterpret_cast<float4*>(base + 4) = make_float4(vals[4], vals[5], vals[6], vals[7]);
    }
}

// ---------------- K2: conv2 via MFMA 16x16x32_f16, XOR-swizzled LDS ----------------
__global__ __launch_bounds__(256) void k_conv2(const float* __restrict__ h1,
                                               const float* __restrict__ w2,
                                               const float* __restrict__ b2,
                                               float* __restrict__ h2) {
    const int b = blockIdx.y;
    const int ty = blockIdx.x / 7, tx = blockIdx.x % 7;    // 7 x 7 tiles of 4x4 pooled
    const int py0 = ty * 4, px0 = tx * 4;
    const int iy0 = py0 * 2, ix0 = px0 * 2;

    __shared__ uint32 tin[12 * 12 * 32];
    __shared__ uint32 wl[1792];

    const int tid = threadIdx.x;

    for (int i = tid; i < 1792; i += 256) {
        const int idx4 = i >> 2, d = i & 3;
        const int oc = idx4 & 15, kcg = idx4 >> 4;
        const int ks = kcg >> 2, c = kcg & 3;
        const int tap = 4 * ks + c;
        uint32 v = 0;
        if (tap < 25 && oc < 10)
            v = packh(w2[(oc * 8 + 2 * d) * 25 + tap],
                      w2[(oc * 8 + 2 * d + 1) * 25 + tap]);
        wl[i] = v;
    }

    const float* hb = h1 + (size_t)b * 8 * 29768;
    for (int s = tid; s < 288; s += 256) {
        const int pos = s >> 1, wqs = s & 1;
        const int r = pos / 12, c = pos % 12;
        const float* base = hb + ((size_t)(iy0 + r) * 61 + ix0 + c) * 8 + wqs * 4;
        const float4 f0 = *reinterpret_cast<const float4*>(base);
        const float4 f1 = *reinterpret_cast<const float4*>(base + 29768);
        const float4 f2 = *reinterpret_cast<const float4*>(base + 2 * 29768);
        const float4 f3 = *reinterpret_cast<const float4*>(base + 3 * 29768);
        const float4 f4 = *reinterpret_cast<const float4*>(base + 4 * 29768);
        const float4 f5 = *reinterpret_cast<const float4*>(base + 5 * 29768);
        const float4 f6 = *reinterpret_cast<const float4*>(base + 6 * 29768);
        const float4 f7 = *reinterpret_cast<const float4*>(base + 7 * 29768);
        const int sw = pos & 7;
        const int bi = pos * 32;
        *reinterpret_cast<uint4*>(&tin[bi + (((wqs * 4 + 0) ^ sw) << 2)]) =
            make_uint4(pkrtz(f0.x, f1.x), pkrtz(f2.x, f3.x), pkrtz(f4.x, f5.x), pkrtz(f6.x, f7.x));
        *reinterpret_cast<uint4*>(&tin[bi + (((wqs * 4 + 1) ^ sw) << 2)]) =
            make_uint4(pkrtz(f0.y, f1.y), pkrtz(f2.y, f3.y), pkrtz(f4.y, f5.y), pkrtz(f6.y, f7.y));
        *reinterpret_cast<uint4*>(&tin[bi + (((wqs * 4 + 2) ^ sw) << 2)]) =
            make_uint4(pkrtz(f0.z, f1.z), pkrtz(f2.z, f3.z), pkrtz(f4.z, f5.z), pkrtz(f6.z, f7.z));
        *reinterpret_cast<uint4*>(&tin[bi + (((wqs * 4 + 3) ^ sw) << 2)]) =
            make_uint4(pkrtz(f0.w, f1.w), pkrtz(f2.w, f3.w), pkrtz(f4.w, f5.w), pkrtz(f6.w, f7.w));
    }

    const int lane = tid & 63;
    const int wv   = tid >> 6;
    const int kc   = lane >> 4;
    const int arow = lane & 15;
    const int q    = arow >> 2, cp = arow & 3;
    const int cpy  = cp >> 1,  cpx = cp & 1;

    int offp[7], sw2[7];
#pragma unroll
    for (int ks = 0; ks < 7; ++ks) {
        int tap = 4 * ks + kc;
        if (tap > 24) tap = 24;
        const int kd = tap / 5, kh = tap % 5;
        const int pos = (2 * wv + cpy + kd) * 12 + (2 * q + cpx + kh);
        offp[ks] = pos * 32;
        sw2[ks]  = pos & 7;
    }

    __syncthreads();

    f16x8 Bf[7];
#pragma unroll
    for (int ks = 0; ks < 7; ++ks) {
        const uint4 t = *reinterpret_cast<const uint4*>(&wl[(ks * 64 + lane) * 4]);
        Bf[ks] = __builtin_bit_cast(f16x8, t);
    }

    f32x4 acc[8];
#pragma unroll
    for (int w = 0; w < 8; ++w) acc[w] = (f32x4)(0.f);

#pragma unroll
    for (int w = 0; w < 8; ++w) {
#pragma unroll
        for (int ks = 0; ks < 7; ++ks) {
            const uint4 a4 = *reinterpret_cast<const uint4*>(
                &tin[offp[ks] + (((w ^ sw2[ks])) << 2)]);
            acc[w] = __builtin_amdgcn_mfma_f32_16x16x32_f16(
                __builtin_bit_cast(f16x8, a4), Bf[ks], acc[w], 0, 0, 0);
        }
    }

    const int oc = lane & 15, qo = lane >> 4;
    const int pi = py0 + wv, pjg = px0 + qo;
    if (oc < 10) {
        const float bb = b2[oc];
        float vals[8];
#pragma unroll
        for (int w = 0; w < 8; ++w) {
            const float m = fmaxf(fmaxf(acc[w][0], acc[w][1]), fmaxf(acc[w][2], acc[w][3]));
            vals[w] = fmaxf(m + bb, 0.f);
        }
        float* base = h2 + ((((size_t)b * 10 + oc) * 28 + pi) * 28 + pjg) * 8;
        *reinterpret_cast<float4*>(base)     = make_float4(vals[0], vals[1], vals[2], vals[3]);
        *reinterpret_cast<float4*>(base + 4) = make_float4(vals[4], vals[5], vals[6], vals[7]);
    }
}

// ---------------- K3: fc1 (62720 -> 32), chunk-per-block: feat staged ONCE ----------
__global__ __launch_bounds__(256) void k_fc1(const float* __restrict__ feat,
                                             const float* __restrict__ w,
                                             float* __restrict__ partials) {
    const int blk = blockIdx.x;
    const int tid = threadIdx.x;

    __shared__ float sf[8 * 392];

    const float4* f4g = reinterpret_cast<const float4*>(feat);
    for (int s = tid; s < 784; s += 256) {
        const int b = s / 98, i = s % 98;
        *reinterpret_cast<float4*>(&sf[(b * 98 + i) * 4]) =
            f4g[(size_t)b * 15680 + blk * 98 + i];
    }
    __syncthreads();

    const int j = tid >> 3, b = tid & 7;
    const float4* wp = reinterpret_cast<const float4*>(w) + (size_t)j * 15680 + blk * 98;
    const float4* fp = reinterpret_cast<const float4*>(&sf[b * 392]);
    float acc = 0.f;
#pragma unroll 7
    for (int i = 0; i < 98; ++i) {
        const float4 wv = wp[i];
        const float4 fv = fp[i];
        acc = fmaf(wv.x, fv.x, fmaf(wv.y, fv.y, fmaf(wv.z, fv.z, fmaf(wv.w, fv.w, acc))));
    }
    partials[(j * 160 + blk) * 8 + b] = acc;
}

// ---------------- K3b: reduce partials + fc2 + tanh + rigid -> rt[64] ----------------
__global__ __launch_bounds__(256) void k_rt(const float* __restrict__ partials,
                                            const float* __restrict__ f1b,
                                            const float* __restrict__ f2w,
                                            const float* __restrict__ f2b,
                                            float* __restrict__ rt) {
    const int tid = threadIdx.x;
    __shared__ float sfo[256];         // [b][j]

    {
        const int j = tid >> 3, b = tid & 7;
        const float* p = partials + (size_t)j * 160 * 8 + b;
        float s = 0.f;
        for (int kc = 0; kc < 160; ++kc) s += p[kc * 8];
        sfo[b * 32 + j] = fmaxf(s + f1b[j], 0.f);
    }
    __syncthreads();
    if (tid < 64) {
        const int b = tid >> 3, t = tid & 7;
        const float* f = &sfo[b * 32];
        float th[6];
#pragma unroll
        for (int i = 0; i < 6; ++i) {
            const int o = t * 6 + i;
            float s = f2b[o];
            const float* wr = f2w + o * 32;
#pragma unroll
            for (int k = 0; k < 32; ++k) s = fmaf(f[k], wr[k], s);
            th[i] = tanhf(s);
        }
        float s0, c0, s1, c1, s2, c2;
        sincosf(PI_F * th[0], &s0, &c0);
        sincosf(PI_F * th[1], &s1, &c1);
        sincosf(PI_F * th[2], &s2, &c2);
        const float R00 = c0 * c1, R10 = s0 * c1, R20 = -s1;
        const float R01 = -s0 * c2 + c0 * s1 * s2;
        const float R11 =  c0 * c2 + s0 * s1 * s2;
        const float R21 =  c1 * s2;
        const float T0 = th[3] * 128.f + 64.f - (64.f * R00 + 64.f * R10 + 4.f * R20);
        const float T1 = th[4] * 128.f + 64.f - (64.f * R01 + 64.f * R11 + 4.f * R21);
        float* o = rt + tid * 8;
        o[0] = R00; o[1] = R10; o[2] = R20; o[3] = T0;
        o[4] = R01; o[5] = R11; o[6] = R21; o[7] = T1;
    }
}

// ---------------- K4: flow + grid + trilinear sample + moved/reg (rt from global) ------
__global__ __launch_bounds__(256) void k_flow_all(const float* __restrict__ x,
                                                  const float* __restrict__ rt,
                                                  const float* __restrict__ pos,
                                                  const float* __restrict__ centers,
                                                  float* __restrict__ outXt,
                                                  float* __restrict__ outGrid,
                                                  float* __restrict__ movedOut,
                                                  float* __restrict__ regOut) {
    const int b = blockIdx.y;
    const int tid = threadIdx.x;
    const int l = blockIdx.x * 256 + tid;

    __shared__ float srt[64];
    __shared__ float sg[768];
    __shared__ float red[128];

    if (tid < 64) srt[tid] = rt[b * 64 + tid];
    __syncthreads();

    const float gi = (float)(l >> 10);
    const float gj = (float)((l >> 3) & 127);
    const float gk = (float)(l & 7);

    const float tsx[8] = {32.f, 32.f, 96.f, 96.f, 32.f, 96.f, 64.f, 64.f};
    const float tsy[8] = {32.f, 96.f, 32.f, 96.f, 64.f, 64.f, 32.f, 96.f};

    float u0 = 0.f, u1 = 0.f, es = 0.f;
#pragma unroll
    for (int t = 0; t < 8; ++t) {
        float dx = gi - tsx[t], dy = gj - tsy[t], dz = gk - 4.f;
        float d = sqrtf(dx * dx + dy * dy + dz * dz);
        float e = expf(-d / 10.f);
        const float4 ra = *reinterpret_cast<const float4*>(&srt[t * 8]);
        const float4 rb = *reinterpret_cast<const float4*>(&srt[t * 8 + 4]);
        float f0 = fmaf(gi, ra.x, fmaf(gj, ra.y, fmaf(gk, ra.z, ra.w)));
        float f1 = fmaf(gi, rb.x, fmaf(gj, rb.y, fmaf(gk, rb.z, rb.w)));
        u0 = fmaf(e, f0, u0);
        u1 = fmaf(e, f1, u1);
        es += e;
    }
    const float inv = 1.f / es;
    const float fs0 = u0 * inv, fs1 = u1 * inv;
    const float nf0 = fs0 * (1.f / 64.f) - 1.f;
    const float nf1 = fs1 * (1.f / 64.f) - 1.f;

    sg[tid * 3 + 0] = 0.f;
    sg[tid * 3 + 1] = nf1;
    sg[tid * 3 + 2] = nf0;
    __syncthreads();
    if (tid < 192) {
        *reinterpret_cast<float4*>(outGrid + (size_t)b * 393216 + (size_t)blockIdx.x * 768 +
                                   tid * 4) = *reinterpret_cast<float4*>(&sg[tid * 4]);
    }

    const float iz = fs0 - 0.5f, iy = fs1 - 0.5f;
    const float z0f = floorf(iz), y0f = floorf(iy);
    const float fz = iz - z0f, fy = iy - y0f;
    const int z0 = (int)z0f, y0 = (int)y0f;
    float s0 = 0.f, s1 = 0.f, s2 = 0.f, s3 = 0.f;
    const float* xb = x + (size_t)b * 4 * 131072;
#pragma unroll
    for (int dz = 0; dz < 2; ++dz) {
        const int zc = z0 + dz;
        if (zc < 0 || zc > 127) continue;
        const float wz = dz ? fz : 1.f - fz;
#pragma unroll
        for (int dy = 0; dy < 2; ++dy) {
            const int yc = y0 + dy;
            if (yc < 0 || yc > 127) continue;
            const float wv = wz * (dy ? fy : 1.f - fy) * 0.5f;
            const float* p = xb + ((size_t)zc * 128 + yc) * 8 + 3;
            s0 = fmaf(wv, p[0] + p[1], s0);
            s1 = fmaf(wv, p[131072] + p[131073], s1);
            s2 = fmaf(wv, p[262144] + p[262145], s2);
            s3 = fmaf(wv, p[393216] + p[393217], s3);
        }
    }
    float* o = outXt + (size_t)b * 4 * 131072 + l;
    o[0] = s0; o[131072] = s1; o[262144] = s2; o[393216] = s3;

    if (blockIdx.x == 0) {
        float nrm = 0.f;
        if (tid < 128) {
            const int p = tid;
            if (p < 100) {
                const float* pp = pos + ((size_t)b * 100 + p) * 3;
                const float p0 = pp[0], p1 = pp[1], p2 = pp[2];
                int i0 = (int)rintf(p0); i0 = i0 < 0 ? 0 : (i0 > 127 ? 127 : i0);
                int i1 = (int)rintf(p1); i1 = i1 < 0 ? 0 : (i1 > 127 ? 127 : i1);
                int i2 = (int)rintf(p2); i2 = i2 < 0 ? 0 : (i2 > 7 ? 7 : i2);
                const float qi = (float)i0, qj = (float)i1, qk = (float)i2;
                float v0 = 0.f, v1 = 0.f, esm = 0.f;
#pragma unroll
                for (int t = 0; t < 8; ++t) {
                    float dx = qi - tsx[t], dy = qj - tsy[t], dz = qk - 4.f;
                    float d = sqrtf(dx * dx + dy * dy + dz * dz);
                    float e = expf(-d / 10.f);
                    const float* r = srt + t * 8;
                    float f0 = fmaf(qi, r[0], fmaf(qj, r[1], fmaf(qk, r[2], r[3])));
                    float f1 = fmaf(qi, r[4], fmaf(qj, r[5], fmaf(qk, r[6], r[7])));
                    v0 = fmaf(e, f0, v0);
                    v1 = fmaf(e, f1, v1);
                    esm += e;
                }
                const float invm = 1.f / esm;
                const float m0 = 2.f * p0 - (0.5f + 0.5f * ((v0 * invm) * (1.f / 64.f) - 1.f)) * 127.f;
                const float m1 = 2.f * p1 - (0.5f + 0.5f * ((v1 * invm) * (1.f / 64.f) - 1.f)) * 127.f;
                const float m2 = 2.f * p2 - 3.5f;
                float* mo = movedOut + ((size_t)b * 100 + p) * 3;
                mo[0] = m0; mo[1] = m1; mo[2] = m2;
                const float* ce = centers + p * 3;
                const float d0 = m0 - ce[0], d1 = m1 - ce[1], d2 = m2 - ce[2];
                nrm = sqrtf(d0 * d0 + d1 * d1 + d2 * d2);
            }
            red[tid] = nrm;
        }
        __syncthreads();
        for (int s = 64; s > 0; s >>= 1) {
            if (tid < s) red[tid] += red[tid + s];
            __syncthreads();
        }
        if (tid == 0) regOut[b] = red[0] * 0.01f;
    }
}

// ---------------- launch ----------------
extern "C" void kernel_launch(void* const* d_in, const int* in_sizes, int n_in,
                              void* d_out, int out_size, void* d_ws, size_t ws_size,
                              hipStream_t stream) {
    const float* x       = (const float*)d_in[0];
    const float* pos     = (const float*)d_in[1];
    const float* centers = (const float*)d_in[2];
    const float* c1w     = (const float*)d_in[3];
    const float* c1b     = (const float*)d_in[4];
    const float* c2w     = (const float*)d_in[5];
    const float* c2b     = (const float*)d_in[6];
    const float* f1w     = (const float*)d_in[7];
    const float* f1b     = (const float*)d_in[8];
    const float* f2w     = (const float*)d_in[9];
    const float* f2b     = (const float*)d_in[10];

    float* out = (float*)d_out;
    float* ws  = (float*)d_ws;

    // workspace layout (floats)
    float* h1       = ws;                      // 8*8*61*61*8   = 1,905,152
    float* h2       = h1 + 1905152;            // 8*10*28*28*8  =   501,760
    float* partials = h2 + 501760;             // 32*160*8      =    40,960
    float* rt       = partials + 40960;        // 64*8          =       512

    // output layout (floats): X_t | grid | reg | moved
    float* outXt    = out;                         // 4,194,304
    float* outGrid  = out + 4194304;               // 3,145,728
    float* outReg   = out + 4194304 + 3145728;     // 8
    float* outMoved = outReg + 8;                  // 2,400

    k_conv1<<<dim3(256, 8), 256, 0, stream>>>(x, c1w, c1b, h1);
    k_conv2<<<dim3(49, 8), 256, 0, stream>>>(h1, c2w, c2b, h2);
    k_fc1<<<160, 256, 0, stream>>>(h2, f1w, partials);
    k_rt<<<1, 256, 0, stream>>>(partials, f1b, f2w, f2b, rt);
    k_flow_all<<<dim3(512, 8), 256, 0, stream>>>(x, rt, pos, centers,
                                                 outXt, outGrid, outMoved, outReg);
}